// Round 18
// baseline (999.431 us; speedup 1.0000x reference)
//
#include <hip/hip_runtime.h>
#include <hip/hip_bf16.h>

// Geo2Vec fused MLP, bf16 MFMA. Round 18: register-lean split-K a-gemms.
// R17's split-K halved A-LDS (the saturated pipe: 87k cyc/block vs MFMA 70k)
// but spilled (160 live regs vs ~128 allocator target -> 2.4GB scratch).
// R18 trims to ~140 live: B 2-deep (1-ahead), A 2-buffer (1-ahead), NO
// cross-gemm prefetch threading. a-gemm: 8 waves = (ks: K-half) x (cg: 64-col
// group), combine via symmetric bf16 cross-dump (proven numerically in R17).
// b-gemm: 8 col-waves x 32 cols, full K, 2-deep pipes.

typedef __attribute__((ext_vector_type(8))) __bf16 bfv8;
typedef __attribute__((ext_vector_type(8))) short s16x8;
typedef __attribute__((ext_vector_type(4))) float f32x4;
typedef __attribute__((ext_vector_type(4))) int i32x4;

__device__ __forceinline__ short f2bf(float f) {
  unsigned u = __builtin_bit_cast(unsigned, f);
  u = (u + 0x7fffu + ((u >> 16) & 1u)) >> 16;
  return (short)u;
}
__device__ __forceinline__ float bf2f(short s) {
  unsigned u = ((unsigned)(unsigned short)s) << 16;
  return __builtin_bit_cast(float, u);
}
__device__ __forceinline__ int swzaddr(int base, int stride, int row, int colbyte) {
  return base + row * stride + (colbyte ^ (((row & 7) << 4) ^ ((row & 8) << 2)));
}
__device__ __forceinline__ void ldsbar() {
  __builtin_amdgcn_sched_barrier(0);
  asm volatile("s_waitcnt lgkmcnt(0)");
  __builtin_amdgcn_s_barrier();
  __builtin_amdgcn_sched_barrier(0);
}

// ---------------- weight pack (interleaved-column frag layout) ----------------
__global__ void pack_weights_kernel(const float* __restrict__ W1a, const float* __restrict__ W1b,
                                    const float* __restrict__ Wa, const float* __restrict__ Wb,
                                    short* __restrict__ ws) {
  int p = blockIdx.x * blockDim.x + threadIdx.x;
  const int P1 = 10240;
  const int P2 = P1 + 8192;
  const int P3 = P2 + 8 * 18432;
  const int P4 = P3 + 8 * 8192;
  if (p >= P4) return;
  const float* src;
  int q;
  if (p < P1)      { src = W1a; q = p; }
  else if (p < P2) { src = W1b; q = p - P1; }
  else if (p < P3) { q = p - P2; int l = q / 18432; q -= l * 18432; src = Wa + l * 147456; }
  else             { q = p - P3; int l = q / 8192;  q -= l * 8192;  src = Wb + l * 65536; }
  const int lane = q & 63, t = q >> 6, nt = t & 15, kt = t >> 4;
  const int k0 = kt * 32 + ((lane >> 4) << 3);
  const int n  = ((nt >> 1) << 5) + ((lane & 15) << 1) + (nt & 1);
  short* dst = ws + (size_t)p * 8;
#pragma unroll
  for (int i = 0; i < 8; ++i) dst[i] = f2bf(src[(size_t)(k0 + i) * 256 + n]);
}

// ---------------- fused MLP ----------------
// LDS (bytes): xyz [0,40960) s640 ; x [40960,73728) s512 ; t [73728,106496) s512
//              stage [106496,139264)
#define XB 40960
#define TB 73728
#define SG 106496

struct AFrag { bfv8 r0, r1, r2, r3; };

__device__ __forceinline__ bfv8 bfrag(const short* __restrict__ wp, int kt, int nt, int lane) {
  const short* base = wp + (((size_t)(kt * 16 + nt)) << 9);  // wave-uniform
  return *(const bfv8*)(base + (lane << 3));
}

// ---- a-gemm K-half: 64 rows x 64 cols over kts [KT0,KT1) ----
template<int KT0, int KT1, int SPLITKT>
__device__ __forceinline__ void khalf_a(const short* lds,
    const short* __restrict__ wp, int ntb, int lane, f32x4 (&acc)[4][4])
{
  constexpr int H = KT1 - KT0;
  const int lo = lane & 15, hi = lane >> 4;
  const int xr  = ((lo & 7) << 4) ^ ((lo & 8) << 2);
  const int hib = hi << 4;
  const char* A1E = (const char*)lds + lo * 640 + ((     hib) ^ xr);
  const char* A1O = (const char*)lds + lo * 640 + ((64 + hib) ^ xr);
  const char* A2E = (const char*)lds + XB + lo * 512 + ((     hib) ^ xr);
  const char* A2O = (const char*)lds + XB + lo * 512 + ((64 + hib) ^ xr);

  auto aLoad = [&](int kt, AFrag& dst) {
    const bool g1 = kt < SPLITKT;
    const int kk  = g1 ? kt : kt - SPLITKT;
    const int st  = g1 ? 640 : 512;
    const char* b = (g1 ? ((kk & 1) ? A1O : A1E) : ((kk & 1) ? A2O : A2E)) + (kk >> 1) * 128;
    dst.r0 = *(const bfv8*)(b);
    dst.r1 = *(const bfv8*)(b + (st << 4));
    dst.r2 = *(const bfv8*)(b + (st << 5));
    dst.r3 = *(const bfv8*)(b + (st << 4) * 3);
  };

  bfv8 bst[2][4];
  AFrag ast[2];
#pragma unroll
  for (int c = 0; c < 4; ++c) bst[0][c] = bfrag(wp, KT0, ntb + c, lane);
  aLoad(KT0, ast[0]);

#pragma unroll
  for (int i = 0; i < H; ++i) {
    const int kt = KT0 + i;
    if (i + 1 < H) {
#pragma unroll
      for (int c = 0; c < 4; ++c) bst[(i + 1) & 1][c] = bfrag(wp, kt + 1, ntb + c, lane);
      aLoad(kt + 1, ast[(i + 1) & 1]);
    }
    const AFrag& ac = ast[i & 1];
    __builtin_amdgcn_s_setprio(1);
#pragma unroll
    for (int ct = 0; ct < 4; ++ct) {
      acc[0][ct] = __builtin_amdgcn_mfma_f32_16x16x32_bf16(ac.r0, bst[i & 1][ct], acc[0][ct], 0, 0, 0);
      acc[1][ct] = __builtin_amdgcn_mfma_f32_16x16x32_bf16(ac.r1, bst[i & 1][ct], acc[1][ct], 0, 0, 0);
      acc[2][ct] = __builtin_amdgcn_mfma_f32_16x16x32_bf16(ac.r2, bst[i & 1][ct], acc[2][ct], 0, 0, 0);
      acc[3][ct] = __builtin_amdgcn_mfma_f32_16x16x32_bf16(ac.r3, bst[i & 1][ct], acc[3][ct], 0, 0, 0);
    }
    __builtin_amdgcn_s_setprio(0);
  }
}

// ---- split-K a-gemm with symmetric bf16 cross-dump combine ----
template<int NKT, int SPLITKT, int H0>
__device__ __forceinline__ void do_gemm_a(short* lds,
    const short* __restrict__ wp, const float* __restrict__ bias,
    int ks, int cg, int lane)
{
  const int lo = lane & 15, hi = lane >> 4;
  const int ntb = cg << 2;
  const float2 bv = *(const float2*)(bias + (cg << 6) + (ks << 5) + (lo << 1));
  f32x4 acc[4][4];
#pragma unroll
  for (int r = 0; r < 4; ++r)
#pragma unroll
    for (int c = 0; c < 4; ++c) acc[r][c] = (f32x4)0.f;

  if (ks == 0) khalf_a<0, H0, SPLITKT>(lds, wp, ntb, lane, acc);
  else         khalf_a<H0, NKT, SPLITKT>(lds, wp, ntb, lane, acc);

  // dump NON-owned 32-col pair as bf16 (cvt_pk pairs match col interleave)
  char* stg = (char*)lds + SG;
  const int wslot = ((ks << 8) + (cg << 6) + lane) << 4;
  const int rslot = (((ks ^ 1) << 8) + (cg << 6) + lane) << 4;
  const int dp = (ks ^ 1) << 1;   // dumped ct base
  const int op = ks << 1;         // owned  ct base
#pragma unroll
  for (int rt = 0; rt < 4; ++rt) {
    i32x4 d;
#pragma unroll
    for (int rr = 0; rr < 4; ++rr) {
      unsigned pk;
      asm("v_cvt_pk_bf16_f32 %0, %1, %2" : "=v"(pk) : "v"(acc[rt][dp][rr]), "v"(acc[rt][dp + 1][rr]));
      d[rr] = (int)pk;
    }
    *(i32x4*)(stg + rt * 8192 + wslot) = d;
  }
  ldsbar();  // dumps visible
  // combine partner's dump into OWN pair, bias+leaky, write t
#pragma unroll
  for (int rt = 0; rt < 4; ++rt) {
    const i32x4 pk = *(const i32x4*)(stg + rt * 8192 + rslot);
#pragma unroll
    for (int rr = 0; rr < 4; ++rr) {
      const unsigned u = (unsigned)pk[rr];
      const float p0 = __builtin_bit_cast(float, u << 16);
      const float p1 = __builtin_bit_cast(float, u & 0xffff0000u);
      float v0 = acc[rt][op][rr]     + p0 + bv.x;
      float v1 = acc[rt][op + 1][rr] + p1 + bv.y;
      v0 = fmaxf(v0, 0.01f * v0); v1 = fmaxf(v1, 0.01f * v1);
      unsigned o;
      asm("v_cvt_pk_bf16_f32 %0, %1, %2" : "=v"(o) : "v"(v0), "v"(v1));
      const int orow = (rt << 4) + (hi << 2) + rr;
      *(unsigned*)((char*)lds + swzaddr(TB, 512, orow, (cg << 7) + (ks << 6) + (lo << 2))) = o;
    }
  }
  ldsbar();  // t complete
}

// ---- b-gemm: 8 col-waves x 32 cols, full K=256 over t ----
__device__ __forceinline__ void do_gemm_b(short* lds,
    const short* __restrict__ wp, const float* __restrict__ bias,
    int w, int lane)
{
  constexpr int NKT = 8;
  const int lo = lane & 15, hi = lane >> 4;
  const int ntb = w << 1;
  const float2 bv = *(const float2*)(bias + (w << 5) + (lo << 1));
  f32x4 acc[4][2];
#pragma unroll
  for (int r = 0; r < 4; ++r) { acc[r][0] = (f32x4)0.f; acc[r][1] = (f32x4)0.f; }

  const int xr  = ((lo & 7) << 4) ^ ((lo & 8) << 2);
  const int hib = hi << 4;
  const char* AE = (const char*)lds + TB + lo * 512 + ((     hib) ^ xr);
  const char* AO = (const char*)lds + TB + lo * 512 + ((64 + hib) ^ xr);

  auto aLoad = [&](int kt, AFrag& dst) {
    const char* b = ((kt & 1) ? AO : AE) + (kt >> 1) * 128;
    dst.r0 = *(const bfv8*)(b);
    dst.r1 = *(const bfv8*)(b + (512 << 4));
    dst.r2 = *(const bfv8*)(b + (512 << 5));
    dst.r3 = *(const bfv8*)(b + (512 << 4) * 3);
  };

  bfv8 bst[2][2];
  AFrag ast[2];
  bst[0][0] = bfrag(wp, 0, ntb, lane); bst[0][1] = bfrag(wp, 0, ntb + 1, lane);
  aLoad(0, ast[0]);

#pragma unroll
  for (int i = 0; i < NKT; ++i) {
    if (i + 1 < NKT) {
      bst[(i + 1) & 1][0] = bfrag(wp, i + 1, ntb, lane);
      bst[(i + 1) & 1][1] = bfrag(wp, i + 1, ntb + 1, lane);
      aLoad(i + 1, ast[(i + 1) & 1]);
    }
    const AFrag& ac = ast[i & 1];
    __builtin_amdgcn_s_setprio(1);
    acc[0][0] = __builtin_amdgcn_mfma_f32_16x16x32_bf16(ac.r0, bst[i & 1][0], acc[0][0], 0, 0, 0);
    acc[0][1] = __builtin_amdgcn_mfma_f32_16x16x32_bf16(ac.r0, bst[i & 1][1], acc[0][1], 0, 0, 0);
    acc[1][0] = __builtin_amdgcn_mfma_f32_16x16x32_bf16(ac.r1, bst[i & 1][0], acc[1][0], 0, 0, 0);
    acc[1][1] = __builtin_amdgcn_mfma_f32_16x16x32_bf16(ac.r1, bst[i & 1][1], acc[1][1], 0, 0, 0);
    acc[2][0] = __builtin_amdgcn_mfma_f32_16x16x32_bf16(ac.r2, bst[i & 1][0], acc[2][0], 0, 0, 0);
    acc[2][1] = __builtin_amdgcn_mfma_f32_16x16x32_bf16(ac.r2, bst[i & 1][1], acc[2][1], 0, 0, 0);
    acc[3][0] = __builtin_amdgcn_mfma_f32_16x16x32_bf16(ac.r3, bst[i & 1][0], acc[3][0], 0, 0, 0);
    acc[3][1] = __builtin_amdgcn_mfma_f32_16x16x32_bf16(ac.r3, bst[i & 1][1], acc[3][1], 0, 0, 0);
    __builtin_amdgcn_s_setprio(0);
  }
  // epilogue: bias (no leaky) + cvt_pk -> b32 stores into x
#pragma unroll
  for (int rt = 0; rt < 4; ++rt)
#pragma unroll
    for (int rr = 0; rr < 4; ++rr) {
      const float v0 = acc[rt][0][rr] + bv.x;
      const float v1 = acc[rt][1][rr] + bv.y;
      unsigned pk;
      asm("v_cvt_pk_bf16_f32 %0, %1, %2" : "=v"(pk) : "v"(v0), "v"(v1));
      const int orow = (rt << 4) + (hi << 2) + rr;
      *(unsigned*)((char*)lds + swzaddr(XB, 512, orow, (w << 6) + (lo << 2))) = pk;
    }
}

__launch_bounds__(512, 1)
__global__ void geo2vec_kernel(const float* __restrict__ xy, const int* __restrict__ idx,
    const float* __restrict__ emb,
    const float* __restrict__ b1a, const float* __restrict__ b1b,
    const float* __restrict__ ba, const float* __restrict__ bb,
    const float* __restrict__ W2, const float* __restrict__ b2,
    const short* __restrict__ wp, float* __restrict__ out)
{
  __shared__ short lds[69632];  // 136 KB (xyz + x + t + 32KB stage)
  const int tid = threadIdx.x;
  const int lane = tid & 63;
  const int w  = __builtin_amdgcn_readfirstlane(tid >> 6);
  const int ks = w >> 2, cg = w & 3;

  // ---- prologue: pos-encode + gather z -> xyz tile (64 x 320 bf16) ----
  {
    const int g = tid >> 3, j = tid & 7;
    const int row = blockIdx.x * 64 + g;
    const float xv = xy[2 * row], yv = xy[2 * row + 1];
    const float rv = sqrtf(xv * xv + yv * yv);
    union { short s[8]; i32x4 v; } tmp;
#pragma unroll
    for (int i = 0; i < 8; ++i) {
      const int c = 8 * j + i;
      float fv;
      if (c < 2)       fv = c ? yv : xv;
      else if (c < 22) { int m = c - 2;  float f = 1.0f + (5.0f / 9.0f) * (m >> 1); fv = sinf(((m & 1) ? yv : xv) * f); }
      else if (c < 42) { int m = c - 22; float f = 1.0f + (5.0f / 9.0f) * (m >> 1); fv = cosf(((m & 1) ? yv : xv) * f); }
      else if (c < 44) fv = (c == 42) ? xv : yv;
      else if (c < 54) fv = sinf(rv * (1.0f + (5.0f / 9.0f) * (c - 44)));
      else             fv = cosf(rv * (1.0f + (5.0f / 9.0f) * (c - 54)));
      tmp.s[i] = f2bf(fv);
    }
    *(i32x4*)((char*)lds + swzaddr(0, 640, g, j << 4)) = tmp.v;
    const float* zr = emb + (size_t)(unsigned)idx[row] * 256;
#pragma unroll
    for (int c4 = 0; c4 < 4; ++c4) {
      const int cel = j * 32 + c4 * 8;
      const float4 f0 = *(const float4*)(zr + cel);
      const float4 f1 = *(const float4*)(zr + cel + 4);
      union { short s[8]; i32x4 v; } t2;
      t2.s[0] = f2bf(f0.x); t2.s[1] = f2bf(f0.y); t2.s[2] = f2bf(f0.z); t2.s[3] = f2bf(f0.w);
      t2.s[4] = f2bf(f1.x); t2.s[5] = f2bf(f1.y); t2.s[6] = f2bf(f1.z); t2.s[7] = f2bf(f1.w);
      *(i32x4*)((char*)lds + swzaddr(0, 640, g, (64 + cel) << 1)) = t2.v;
    }
  }
  ldsbar();

  // layer 1: a (split-K over xyz, K=320) -> t ; b (K=256) -> x
  do_gemm_a<10, 10, 5>(lds, wp, b1a, ks, cg, lane);
  do_gemm_b(lds, wp + 81920, b1b, w, lane);
  ldsbar();  // x ready
  // 8 mid layers
  for (int l = 0; l < 8; ++l) {
    const short* wa = wp + 147456 + l * 147456;
    const short* wb = wp + 1327104 + l * 65536;
    do_gemm_a<18, 10, 9>(lds, wa, ba + l * 256, ks, cg, lane);
    do_gemm_b(lds, wb, bb + l * 256, w, lane);
    ldsbar();  // x ready for next a (or final reduce)
  }
  // final: out = x @ W2 + b2 ; 8 threads per row, width-8 shuffle reduce
  {
    const int r = tid >> 3, j = tid & 7;
    float sum = 0.f;
#pragma unroll
    for (int h = 0; h < 4; ++h) {
      const int cb = 64 * j + 16 * h;
      const s16x8 v = *(const s16x8*)((const char*)lds + swzaddr(XB, 512, r, cb));
      const int c0 = 32 * j + 8 * h;
      const float4 w0 = *(const float4*)(W2 + c0);
      const float4 w1 = *(const float4*)(W2 + c0 + 4);
      sum += bf2f(v[0]) * w0.x + bf2f(v[1]) * w0.y + bf2f(v[2]) * w0.z + bf2f(v[3]) * w0.w;
      sum += bf2f(v[4]) * w1.x + bf2f(v[5]) * w1.y + bf2f(v[6]) * w1.z + bf2f(v[7]) * w1.w;
    }
    sum += __shfl_xor(sum, 1); sum += __shfl_xor(sum, 2); sum += __shfl_xor(sum, 4);
    if (j == 0) out[blockIdx.x * 64 + r] = sum + b2[0];
  }
}

extern "C" void kernel_launch(void* const* d_in, const int* in_sizes, int n_in,
                              void* d_out, int out_size, void* d_ws, size_t ws_size,
                              hipStream_t stream) {
  const float* xy  = (const float*)d_in[0];
  const int*   idx = (const int*)d_in[1];
  const float* emb = (const float*)d_in[2];
  const float* W1a = (const float*)d_in[3];
  const float* b1a = (const float*)d_in[4];
  const float* W1b = (const float*)d_in[5];
  const float* b1b = (const float*)d_in[6];
  const float* Wa  = (const float*)d_in[7];
  const float* ba  = (const float*)d_in[8];
  const float* Wb  = (const float*)d_in[9];
  const float* bb  = (const float*)d_in[10];
  const float* W2  = (const float*)d_in[11];
  const float* b2  = (const float*)d_in[12];
  short* ws = (short*)d_ws;
  const int B = in_sizes[1];

  hipLaunchKernelGGL(pack_weights_kernel, dim3(904), dim3(256), 0, stream,
                     W1a, W1b, Wa, Wb, ws);
  hipLaunchKernelGGL(geo2vec_kernel, dim3(B / 64), dim3(512), 0, stream,
                     xy, idx, emb, b1a, b1b, ba, bb, W2, b2, ws, (float*)d_out);
}

// Round 19
// 504.911 us; speedup vs baseline: 1.9794x; 1.9794x over previous
//
#include <hip/hip_runtime.h>
#include <hip/hip_bf16.h>

// Geo2Vec fused MLP, bf16 MFMA. Round 19: R18 split-K with COMPILE-TIME
// combine indices. R17/R18's identical 2.36GB scratch traffic was rule #20:
// acc[rt][dp] with runtime dp=f(ks) put the whole accumulator in scratch.
// Fix: template do_gemm_a on KS (wave-uniform branch dispatch) so every acc
// index is constexpr. Barrier counts match across the branch arms.

typedef __attribute__((ext_vector_type(8))) __bf16 bfv8;
typedef __attribute__((ext_vector_type(8))) short s16x8;
typedef __attribute__((ext_vector_type(4))) float f32x4;
typedef __attribute__((ext_vector_type(4))) int i32x4;

__device__ __forceinline__ short f2bf(float f) {
  unsigned u = __builtin_bit_cast(unsigned, f);
  u = (u + 0x7fffu + ((u >> 16) & 1u)) >> 16;
  return (short)u;
}
__device__ __forceinline__ float bf2f(short s) {
  unsigned u = ((unsigned)(unsigned short)s) << 16;
  return __builtin_bit_cast(float, u);
}
__device__ __forceinline__ int swzaddr(int base, int stride, int row, int colbyte) {
  return base + row * stride + (colbyte ^ (((row & 7) << 4) ^ ((row & 8) << 2)));
}
__device__ __forceinline__ void ldsbar() {
  __builtin_amdgcn_sched_barrier(0);
  asm volatile("s_waitcnt lgkmcnt(0)");
  __builtin_amdgcn_s_barrier();
  __builtin_amdgcn_sched_barrier(0);
}

// ---------------- weight pack (interleaved-column frag layout) ----------------
__global__ void pack_weights_kernel(const float* __restrict__ W1a, const float* __restrict__ W1b,
                                    const float* __restrict__ Wa, const float* __restrict__ Wb,
                                    short* __restrict__ ws) {
  int p = blockIdx.x * blockDim.x + threadIdx.x;
  const int P1 = 10240;
  const int P2 = P1 + 8192;
  const int P3 = P2 + 8 * 18432;
  const int P4 = P3 + 8 * 8192;
  if (p >= P4) return;
  const float* src;
  int q;
  if (p < P1)      { src = W1a; q = p; }
  else if (p < P2) { src = W1b; q = p - P1; }
  else if (p < P3) { q = p - P2; int l = q / 18432; q -= l * 18432; src = Wa + l * 147456; }
  else             { q = p - P3; int l = q / 8192;  q -= l * 8192;  src = Wb + l * 65536; }
  const int lane = q & 63, t = q >> 6, nt = t & 15, kt = t >> 4;
  const int k0 = kt * 32 + ((lane >> 4) << 3);
  const int n  = ((nt >> 1) << 5) + ((lane & 15) << 1) + (nt & 1);
  short* dst = ws + (size_t)p * 8;
#pragma unroll
  for (int i = 0; i < 8; ++i) dst[i] = f2bf(src[(size_t)(k0 + i) * 256 + n]);
}

// ---------------- fused MLP ----------------
// LDS (bytes): xyz [0,40960) s640 ; x [40960,73728) s512 ; t [73728,106496) s512
//              stage [106496,139264)
#define XB 40960
#define TB 73728
#define SG 106496

struct AFrag { bfv8 r0, r1, r2, r3; };

__device__ __forceinline__ bfv8 bfrag(const short* __restrict__ wp, int kt, int nt, int lane) {
  const short* base = wp + (((size_t)(kt * 16 + nt)) << 9);  // wave-uniform
  return *(const bfv8*)(base + (lane << 3));
}

// ---- a-gemm K-half: 64 rows x 64 cols over kts [KT0,KT1) ----
template<int KT0, int KT1, int SPLITKT>
__device__ __forceinline__ void khalf_a(const short* lds,
    const short* __restrict__ wp, int ntb, int lane, f32x4 (&acc)[4][4])
{
  constexpr int H = KT1 - KT0;
  const int lo = lane & 15, hi = lane >> 4;
  const int xr  = ((lo & 7) << 4) ^ ((lo & 8) << 2);
  const int hib = hi << 4;
  const char* A1E = (const char*)lds + lo * 640 + ((     hib) ^ xr);
  const char* A1O = (const char*)lds + lo * 640 + ((64 + hib) ^ xr);
  const char* A2E = (const char*)lds + XB + lo * 512 + ((     hib) ^ xr);
  const char* A2O = (const char*)lds + XB + lo * 512 + ((64 + hib) ^ xr);

  auto aLoad = [&](int kt, AFrag& dst) {
    const bool g1 = kt < SPLITKT;
    const int kk  = g1 ? kt : kt - SPLITKT;
    const int st  = g1 ? 640 : 512;
    const char* b = (g1 ? ((kk & 1) ? A1O : A1E) : ((kk & 1) ? A2O : A2E)) + (kk >> 1) * 128;
    dst.r0 = *(const bfv8*)(b);
    dst.r1 = *(const bfv8*)(b + (st << 4));
    dst.r2 = *(const bfv8*)(b + (st << 5));
    dst.r3 = *(const bfv8*)(b + (st << 4) * 3);
  };

  bfv8 bst[2][4];
  AFrag ast[2];
#pragma unroll
  for (int c = 0; c < 4; ++c) bst[0][c] = bfrag(wp, KT0, ntb + c, lane);
  aLoad(KT0, ast[0]);

#pragma unroll
  for (int i = 0; i < H; ++i) {
    const int kt = KT0 + i;
    if (i + 1 < H) {
#pragma unroll
      for (int c = 0; c < 4; ++c) bst[(i + 1) & 1][c] = bfrag(wp, kt + 1, ntb + c, lane);
      aLoad(kt + 1, ast[(i + 1) & 1]);
    }
    const AFrag& ac = ast[i & 1];
    __builtin_amdgcn_s_setprio(1);
#pragma unroll
    for (int ct = 0; ct < 4; ++ct) {
      acc[0][ct] = __builtin_amdgcn_mfma_f32_16x16x32_bf16(ac.r0, bst[i & 1][ct], acc[0][ct], 0, 0, 0);
      acc[1][ct] = __builtin_amdgcn_mfma_f32_16x16x32_bf16(ac.r1, bst[i & 1][ct], acc[1][ct], 0, 0, 0);
      acc[2][ct] = __builtin_amdgcn_mfma_f32_16x16x32_bf16(ac.r2, bst[i & 1][ct], acc[2][ct], 0, 0, 0);
      acc[3][ct] = __builtin_amdgcn_mfma_f32_16x16x32_bf16(ac.r3, bst[i & 1][ct], acc[3][ct], 0, 0, 0);
    }
    __builtin_amdgcn_s_setprio(0);
  }
}

// ---- split-K a-gemm, KS compile-time: all acc indices constexpr ----
template<int NKT, int SPLITKT, int H0, int KS>
__device__ __forceinline__ void do_gemm_a_ks(short* lds,
    const short* __restrict__ wp, const float* __restrict__ bias,
    int cg, int lane)
{
  constexpr int dp = (KS ^ 1) << 1;   // dumped (non-owned) ct base
  constexpr int op = KS << 1;         // owned ct base
  const int lo = lane & 15, hi = lane >> 4;
  const int ntb = cg << 2;
  const float2 bv = *(const float2*)(bias + (cg << 6) + (KS << 5) + (lo << 1));
  f32x4 acc[4][4];
#pragma unroll
  for (int r = 0; r < 4; ++r)
#pragma unroll
    for (int c = 0; c < 4; ++c) acc[r][c] = (f32x4)0.f;

  if (KS == 0) khalf_a<0, H0, SPLITKT>(lds, wp, ntb, lane, acc);
  else         khalf_a<H0, NKT, SPLITKT>(lds, wp, ntb, lane, acc);

  // dump NON-owned 32-col pair as bf16 (cvt_pk pairs match col interleave)
  char* stg = (char*)lds + SG;
  const int wslot = ((KS << 8) + (cg << 6) + lane) << 4;
  const int rslot = (((KS ^ 1) << 8) + (cg << 6) + lane) << 4;
#pragma unroll
  for (int rt = 0; rt < 4; ++rt) {
    i32x4 d;
#pragma unroll
    for (int rr = 0; rr < 4; ++rr) {
      unsigned pk;
      asm("v_cvt_pk_bf16_f32 %0, %1, %2" : "=v"(pk) : "v"(acc[rt][dp][rr]), "v"(acc[rt][dp + 1][rr]));
      d[rr] = (int)pk;
    }
    *(i32x4*)(stg + rt * 8192 + wslot) = d;
  }
  ldsbar();  // dumps visible
  // combine partner's dump into OWN pair, bias+leaky, write t
#pragma unroll
  for (int rt = 0; rt < 4; ++rt) {
    const i32x4 pk = *(const i32x4*)(stg + rt * 8192 + rslot);
#pragma unroll
    for (int rr = 0; rr < 4; ++rr) {
      const unsigned u = (unsigned)pk[rr];
      const float p0 = __builtin_bit_cast(float, u << 16);
      const float p1 = __builtin_bit_cast(float, u & 0xffff0000u);
      float v0 = acc[rt][op][rr]     + p0 + bv.x;
      float v1 = acc[rt][op + 1][rr] + p1 + bv.y;
      v0 = fmaxf(v0, 0.01f * v0); v1 = fmaxf(v1, 0.01f * v1);
      unsigned o;
      asm("v_cvt_pk_bf16_f32 %0, %1, %2" : "=v"(o) : "v"(v0), "v"(v1));
      const int orow = (rt << 4) + (hi << 2) + rr;
      *(unsigned*)((char*)lds + swzaddr(TB, 512, orow, (cg << 7) + (KS << 6) + (lo << 2))) = o;
    }
  }
  ldsbar();  // t complete
}

// ---- b-gemm: 8 col-waves x 32 cols, full K=256 over t ----
__device__ __forceinline__ void do_gemm_b(short* lds,
    const short* __restrict__ wp, const float* __restrict__ bias,
    int w, int lane)
{
  constexpr int NKT = 8;
  const int lo = lane & 15, hi = lane >> 4;
  const int ntb = w << 1;
  const float2 bv = *(const float2*)(bias + (w << 5) + (lo << 1));
  f32x4 acc[4][2];
#pragma unroll
  for (int r = 0; r < 4; ++r) { acc[r][0] = (f32x4)0.f; acc[r][1] = (f32x4)0.f; }

  const int xr  = ((lo & 7) << 4) ^ ((lo & 8) << 2);
  const int hib = hi << 4;
  const char* AE = (const char*)lds + TB + lo * 512 + ((     hib) ^ xr);
  const char* AO = (const char*)lds + TB + lo * 512 + ((64 + hib) ^ xr);

  auto aLoad = [&](int kt, AFrag& dst) {
    const char* b = ((kt & 1) ? AO : AE) + (kt >> 1) * 128;
    dst.r0 = *(const bfv8*)(b);
    dst.r1 = *(const bfv8*)(b + (512 << 4));
    dst.r2 = *(const bfv8*)(b + (512 << 5));
    dst.r3 = *(const bfv8*)(b + (512 << 4) * 3);
  };

  bfv8 bst[2][2];
  AFrag ast[2];
  bst[0][0] = bfrag(wp, 0, ntb, lane); bst[0][1] = bfrag(wp, 0, ntb + 1, lane);
  aLoad(0, ast[0]);

#pragma unroll
  for (int i = 0; i < NKT; ++i) {
    if (i + 1 < NKT) {
      bst[(i + 1) & 1][0] = bfrag(wp, i + 1, ntb, lane);
      bst[(i + 1) & 1][1] = bfrag(wp, i + 1, ntb + 1, lane);
      aLoad(i + 1, ast[(i + 1) & 1]);
    }
    const AFrag& ac = ast[i & 1];
    __builtin_amdgcn_s_setprio(1);
    acc[0][0] = __builtin_amdgcn_mfma_f32_16x16x32_bf16(ac.r0, bst[i & 1][0], acc[0][0], 0, 0, 0);
    acc[0][1] = __builtin_amdgcn_mfma_f32_16x16x32_bf16(ac.r0, bst[i & 1][1], acc[0][1], 0, 0, 0);
    acc[1][0] = __builtin_amdgcn_mfma_f32_16x16x32_bf16(ac.r1, bst[i & 1][0], acc[1][0], 0, 0, 0);
    acc[1][1] = __builtin_amdgcn_mfma_f32_16x16x32_bf16(ac.r1, bst[i & 1][1], acc[1][1], 0, 0, 0);
    acc[2][0] = __builtin_amdgcn_mfma_f32_16x16x32_bf16(ac.r2, bst[i & 1][0], acc[2][0], 0, 0, 0);
    acc[2][1] = __builtin_amdgcn_mfma_f32_16x16x32_bf16(ac.r2, bst[i & 1][1], acc[2][1], 0, 0, 0);
    acc[3][0] = __builtin_amdgcn_mfma_f32_16x16x32_bf16(ac.r3, bst[i & 1][0], acc[3][0], 0, 0, 0);
    acc[3][1] = __builtin_amdgcn_mfma_f32_16x16x32_bf16(ac.r3, bst[i & 1][1], acc[3][1], 0, 0, 0);
    __builtin_amdgcn_s_setprio(0);
  }
  // epilogue: bias (no leaky) + cvt_pk -> b32 stores into x
#pragma unroll
  for (int rt = 0; rt < 4; ++rt)
#pragma unroll
    for (int rr = 0; rr < 4; ++rr) {
      const float v0 = acc[rt][0][rr] + bv.x;
      const float v1 = acc[rt][1][rr] + bv.y;
      unsigned pk;
      asm("v_cvt_pk_bf16_f32 %0, %1, %2" : "=v"(pk) : "v"(v0), "v"(v1));
      const int orow = (rt << 4) + (hi << 2) + rr;
      *(unsigned*)((char*)lds + swzaddr(XB, 512, orow, (w << 6) + (lo << 2))) = pk;
    }
}

__launch_bounds__(512, 1)
__global__ void geo2vec_kernel(const float* __restrict__ xy, const int* __restrict__ idx,
    const float* __restrict__ emb,
    const float* __restrict__ b1a, const float* __restrict__ b1b,
    const float* __restrict__ ba, const float* __restrict__ bb,
    const float* __restrict__ W2, const float* __restrict__ b2,
    const short* __restrict__ wp, float* __restrict__ out)
{
  __shared__ short lds[69632];  // 136 KB (xyz + x + t + 32KB stage)
  const int tid = threadIdx.x;
  const int lane = tid & 63;
  const int w  = __builtin_amdgcn_readfirstlane(tid >> 6);
  const int ks = w >> 2, cg = w & 3;

  // ---- prologue: pos-encode + gather z -> xyz tile (64 x 320 bf16) ----
  {
    const int g = tid >> 3, j = tid & 7;
    const int row = blockIdx.x * 64 + g;
    const float xv = xy[2 * row], yv = xy[2 * row + 1];
    const float rv = sqrtf(xv * xv + yv * yv);
    union { short s[8]; i32x4 v; } tmp;
#pragma unroll
    for (int i = 0; i < 8; ++i) {
      const int c = 8 * j + i;
      float fv;
      if (c < 2)       fv = c ? yv : xv;
      else if (c < 22) { int m = c - 2;  float f = 1.0f + (5.0f / 9.0f) * (m >> 1); fv = sinf(((m & 1) ? yv : xv) * f); }
      else if (c < 42) { int m = c - 22; float f = 1.0f + (5.0f / 9.0f) * (m >> 1); fv = cosf(((m & 1) ? yv : xv) * f); }
      else if (c < 44) fv = (c == 42) ? xv : yv;
      else if (c < 54) fv = sinf(rv * (1.0f + (5.0f / 9.0f) * (c - 44)));
      else             fv = cosf(rv * (1.0f + (5.0f / 9.0f) * (c - 54)));
      tmp.s[i] = f2bf(fv);
    }
    *(i32x4*)((char*)lds + swzaddr(0, 640, g, j << 4)) = tmp.v;
    const float* zr = emb + (size_t)(unsigned)idx[row] * 256;
#pragma unroll
    for (int c4 = 0; c4 < 4; ++c4) {
      const int cel = j * 32 + c4 * 8;
      const float4 f0 = *(const float4*)(zr + cel);
      const float4 f1 = *(const float4*)(zr + cel + 4);
      union { short s[8]; i32x4 v; } t2;
      t2.s[0] = f2bf(f0.x); t2.s[1] = f2bf(f0.y); t2.s[2] = f2bf(f0.z); t2.s[3] = f2bf(f0.w);
      t2.s[4] = f2bf(f1.x); t2.s[5] = f2bf(f1.y); t2.s[6] = f2bf(f1.z); t2.s[7] = f2bf(f1.w);
      *(i32x4*)((char*)lds + swzaddr(0, 640, g, (64 + cel) << 1)) = t2.v;
    }
  }
  ldsbar();

  // layer 1: a (split-K over xyz, K=320) -> t ; b (K=256) -> x
  if (ks == 0) do_gemm_a_ks<10, 10, 5, 0>(lds, wp, b1a, cg, lane);
  else         do_gemm_a_ks<10, 10, 5, 1>(lds, wp, b1a, cg, lane);
  do_gemm_b(lds, wp + 81920, b1b, w, lane);
  ldsbar();  // x ready
  // 8 mid layers
  for (int l = 0; l < 8; ++l) {
    const short* wa = wp + 147456 + l * 147456;
    const short* wb = wp + 1327104 + l * 65536;
    if (ks == 0) do_gemm_a_ks<18, 10, 9, 0>(lds, wa, ba + l * 256, cg, lane);
    else         do_gemm_a_ks<18, 10, 9, 1>(lds, wa, ba + l * 256, cg, lane);
    do_gemm_b(lds, wb, bb + l * 256, w, lane);
    ldsbar();  // x ready for next a (or final reduce)
  }
  // final: out = x @ W2 + b2 ; 8 threads per row, width-8 shuffle reduce
  {
    const int r = tid >> 3, j = tid & 7;
    float sum = 0.f;
#pragma unroll
    for (int h = 0; h < 4; ++h) {
      const int cb = 64 * j + 16 * h;
      const s16x8 v = *(const s16x8*)((const char*)lds + swzaddr(XB, 512, r, cb));
      const int c0 = 32 * j + 8 * h;
      const float4 w0 = *(const float4*)(W2 + c0);
      const float4 w1 = *(const float4*)(W2 + c0 + 4);
      sum += bf2f(v[0]) * w0.x + bf2f(v[1]) * w0.y + bf2f(v[2]) * w0.z + bf2f(v[3]) * w0.w;
      sum += bf2f(v[4]) * w1.x + bf2f(v[5]) * w1.y + bf2f(v[6]) * w1.z + bf2f(v[7]) * w1.w;
    }
    sum += __shfl_xor(sum, 1); sum += __shfl_xor(sum, 2); sum += __shfl_xor(sum, 4);
    if (j == 0) out[blockIdx.x * 64 + r] = sum + b2[0];
  }
}

extern "C" void kernel_launch(void* const* d_in, const int* in_sizes, int n_in,
                              void* d_out, int out_size, void* d_ws, size_t ws_size,
                              hipStream_t stream) {
  const float* xy  = (const float*)d_in[0];
  const int*   idx = (const int*)d_in[1];
  const float* emb = (const float*)d_in[2];
  const float* W1a = (const float*)d_in[3];
  const float* b1a = (const float*)d_in[4];
  const float* W1b = (const float*)d_in[5];
  const float* b1b = (const float*)d_in[6];
  const float* Wa  = (const float*)d_in[7];
  const float* ba  = (const float*)d_in[8];
  const float* Wb  = (const float*)d_in[9];
  const float* bb  = (const float*)d_in[10];
  const float* W2  = (const float*)d_in[11];
  const float* b2  = (const float*)d_in[12];
  short* ws = (short*)d_ws;
  const int B = in_sizes[1];

  hipLaunchKernelGGL(pack_weights_kernel, dim3(904), dim3(256), 0, stream,
                     W1a, W1b, Wa, Wb, ws);
  hipLaunchKernelGGL(geo2vec_kernel, dim3(B / 64), dim3(512), 0, stream,
                     xy, idx, emb, b1a, b1b, ba, bb, W2, b2, ws, (float*)d_out);
}

// Round 20
// 481.872 us; speedup vs baseline: 2.0741x; 1.0478x over previous
//
#include <hip/hip_runtime.h>
#include <hip/hip_bf16.h>

// Geo2Vec fused MLP, bf16 MFMA. Round 20: R16 structure at BM=48 so LDS =
// 78KB -> TWO independent blocks per CU (4 waves/SIMD, decorrelated barriers;
// one block's MFMA covers the other's loads/barrier drains). Geometry-only
// change from R16 (best, 472us): 3 row-tiles, acc 24 regs, row clamp + output
// guard for the 131072 % 48 tail. launch_bounds(512,4) pins VGPR<=128.

typedef __attribute__((ext_vector_type(8))) __bf16 bfv8;
typedef __attribute__((ext_vector_type(8))) short s16x8;
typedef __attribute__((ext_vector_type(4))) float f32x4;
typedef __attribute__((ext_vector_type(4))) int i32x4;

__device__ __forceinline__ short f2bf(float f) {
  unsigned u = __builtin_bit_cast(unsigned, f);
  u = (u + 0x7fffu + ((u >> 16) & 1u)) >> 16;
  return (short)u;
}
__device__ __forceinline__ float bf2f(short s) {
  unsigned u = ((unsigned)(unsigned short)s) << 16;
  return __builtin_bit_cast(float, u);
}
__device__ __forceinline__ int swzaddr(int base, int stride, int row, int colbyte) {
  return base + row * stride + (colbyte ^ (((row & 7) << 4) ^ ((row & 8) << 2)));
}
// LDS-visibility barrier that does NOT drain vmcnt.
__device__ __forceinline__ void ldsbar() {
  __builtin_amdgcn_sched_barrier(0);
  asm volatile("s_waitcnt lgkmcnt(0)");
  __builtin_amdgcn_s_barrier();
  __builtin_amdgcn_sched_barrier(0);
}

// ---------------- weight pack (interleaved-column frag layout) ----------------
__global__ void pack_weights_kernel(const float* __restrict__ W1a, const float* __restrict__ W1b,
                                    const float* __restrict__ Wa, const float* __restrict__ Wb,
                                    short* __restrict__ ws) {
  int p = blockIdx.x * blockDim.x + threadIdx.x;
  const int P1 = 10240;
  const int P2 = P1 + 8192;
  const int P3 = P2 + 8 * 18432;
  const int P4 = P3 + 8 * 8192;
  if (p >= P4) return;
  const float* src;
  int q;
  if (p < P1)      { src = W1a; q = p; }
  else if (p < P2) { src = W1b; q = p - P1; }
  else if (p < P3) { q = p - P2; int l = q / 18432; q -= l * 18432; src = Wa + l * 147456; }
  else             { q = p - P3; int l = q / 8192;  q -= l * 8192;  src = Wb + l * 65536; }
  const int lane = q & 63, t = q >> 6, nt = t & 15, kt = t >> 4;
  const int k0 = kt * 32 + ((lane >> 4) << 3);
  const int n  = ((nt >> 1) << 5) + ((lane & 15) << 1) + (nt & 1);
  short* dst = ws + (size_t)p * 8;
#pragma unroll
  for (int i = 0; i < 8; ++i) dst[i] = f2bf(src[(size_t)(k0 + i) * 256 + n]);
}

// ---------------- fused MLP ----------------
// LDS (bytes): xyz [0,30720) s640 ; x [30720,55296) s512 ; t [55296,79872) s512
#define XB 30720
#define TB 55296

struct BPre { bfv8 b0, b1; };
struct AFrag { bfv8 r0, r1, r2; };
struct Pre { BPre b; AFrag a; };

__device__ __forceinline__ bfv8 bfrag(const short* __restrict__ wp, int kt, int nt, int lane) {
  const short* base = wp + (((size_t)(kt * 16 + nt)) << 9);  // wave-uniform
  return *(const bfv8*)(base + (lane << 3));
}

template<int NKT, int SPLITKT, bool LEAKY, bool MIDBAR, bool PRE_A, bool PRE_NEXT_A>
__device__ __forceinline__ Pre do_gemm(short* lds,
    int a1Base, int a1S, int a2Base, int a2S,
    const short* __restrict__ wp, const short* __restrict__ wpn,
    const float* __restrict__ bias, int outBase,
    int wc, int lane, Pre pre)
{
  const int lo = lane & 15, hi = lane >> 4;
  const int ntb = wc << 1;
  const float2 bv = *(const float2*)(bias + (wc << 5) + (lo << 1));
  f32x4 acc[3][2];
#pragma unroll
  for (int r = 0; r < 3; ++r) { acc[r][0] = (f32x4)0.f; acc[r][1] = (f32x4)0.f; }

  // Decomposed swizzle bases: addr = base[kk&1] + (kk>>1)*128 + rt*(stride*16)
  const int xr  = ((lo & 7) << 4) ^ ((lo & 8) << 2);
  const int hib = hi << 4;
  const char* A1E = (const char*)lds + a1Base + lo * a1S + ((     hib) ^ xr);
  const char* A1O = (const char*)lds + a1Base + lo * a1S + ((64 + hib) ^ xr);
  const char* A2E = (const char*)lds + a2Base + lo * a2S + ((     hib) ^ xr);
  const char* A2O = (const char*)lds + a2Base + lo * a2S + ((64 + hib) ^ xr);

  auto aLoad = [&](int kt, AFrag& dst) {
    const bool g1 = kt < SPLITKT;
    const int kk  = g1 ? kt : kt - SPLITKT;
    const int st  = g1 ? a1S : a2S;
    const char* b = (g1 ? ((kk & 1) ? A1O : A1E) : ((kk & 1) ? A2O : A2E)) + (kk >> 1) * 128;
    dst.r0 = *(const bfv8*)(b);
    dst.r1 = *(const bfv8*)(b + (st << 4));
    dst.r2 = *(const bfv8*)(b + (st << 5));
  };

  bfv8 bst[4][2];
  AFrag ast[3];
  bst[0][0] = pre.b.b0; bst[0][1] = pre.b.b1;
  if (NKT > 1) { bst[1][0] = bfrag(wp, 1, ntb, lane); bst[1][1] = bfrag(wp, 1, ntb + 1, lane); }
  if (NKT > 2) { bst[2][0] = bfrag(wp, 2, ntb, lane); bst[2][1] = bfrag(wp, 2, ntb + 1, lane); }
  if (PRE_A) ast[0] = pre.a; else aLoad(0, ast[0]);
  if (NKT > 1) aLoad(1, ast[1]);
  Pre nxt;

#pragma unroll
  for (int i = 0; i < NKT; ++i) {
    // hidden barrier: x-region becomes visible here; kt 0..SPLITKT-1 only read xyz
    if (MIDBAR && i == SPLITKT - 2) ldsbar();
    if (i + 3 < NKT) {
      bst[(i + 3) & 3][0] = bfrag(wp, i + 3, ntb, lane);
      bst[(i + 3) & 3][1] = bfrag(wp, i + 3, ntb + 1, lane);
    } else if (i + 3 == NKT || (NKT <= 3 && i == 0)) {  // next gemm's first B frags
      nxt.b.b0 = bfrag(wpn, 0, ntb, lane);
      nxt.b.b1 = bfrag(wpn, 0, ntb + 1, lane);
    }
    if (i + 2 < NKT) aLoad(i + 2, ast[(i + 2) % 3]);
    if (PRE_NEXT_A && i == NKT - 1) {  // next gemm-a's kt0 A-frags (xyz, immutable)
      const char* bx = (const char*)lds + lo * 640 + (hib ^ xr);
      nxt.a.r0 = *(const bfv8*)(bx);
      nxt.a.r1 = *(const bfv8*)(bx + 640 * 16);
      nxt.a.r2 = *(const bfv8*)(bx + 640 * 32);
    }
    const AFrag& ac = ast[i % 3];
    __builtin_amdgcn_s_setprio(1);
    acc[0][0] = __builtin_amdgcn_mfma_f32_16x16x32_bf16(ac.r0, bst[i & 3][0], acc[0][0], 0, 0, 0);
    acc[0][1] = __builtin_amdgcn_mfma_f32_16x16x32_bf16(ac.r0, bst[i & 3][1], acc[0][1], 0, 0, 0);
    acc[1][0] = __builtin_amdgcn_mfma_f32_16x16x32_bf16(ac.r1, bst[i & 3][0], acc[1][0], 0, 0, 0);
    acc[1][1] = __builtin_amdgcn_mfma_f32_16x16x32_bf16(ac.r1, bst[i & 3][1], acc[1][1], 0, 0, 0);
    acc[2][0] = __builtin_amdgcn_mfma_f32_16x16x32_bf16(ac.r2, bst[i & 3][0], acc[2][0], 0, 0, 0);
    acc[2][1] = __builtin_amdgcn_mfma_f32_16x16x32_bf16(ac.r2, bst[i & 3][1], acc[2][1], 0, 0, 0);
    __builtin_amdgcn_s_setprio(0);
  }
  // epilogue: bias + leaky + cvt_pk(2 bf16) -> one b32 store per pair
#pragma unroll
  for (int rt = 0; rt < 3; ++rt)
#pragma unroll
    for (int rr = 0; rr < 4; ++rr) {
      float v0 = acc[rt][0][rr] + bv.x;
      float v1 = acc[rt][1][rr] + bv.y;
      if (LEAKY) { v0 = fmaxf(v0, 0.01f * v0); v1 = fmaxf(v1, 0.01f * v1); }
      unsigned pk;
      asm("v_cvt_pk_bf16_f32 %0, %1, %2" : "=v"(pk) : "v"(v0), "v"(v1));
      const int orow = (rt << 4) + (hi << 2) + rr;
      *(unsigned*)((char*)lds + swzaddr(outBase, 512, orow, (wc << 6) + (lo << 2))) = pk;
    }
  return nxt;
}

__launch_bounds__(512, 4)
__global__ void geo2vec_kernel(const float* __restrict__ xy, const int* __restrict__ idx,
    const float* __restrict__ emb,
    const float* __restrict__ b1a, const float* __restrict__ b1b,
    const float* __restrict__ ba, const float* __restrict__ bb,
    const float* __restrict__ W2, const float* __restrict__ b2,
    const short* __restrict__ wp, float* __restrict__ out, int Btot)
{
  __shared__ short lds[39936];  // 78 KB -> 2 blocks/CU
  const int tid = threadIdx.x;
  const int lane = tid & 63;
  const int wc = __builtin_amdgcn_readfirstlane(tid >> 6);  // wave = col group

  Pre pre;
  pre.b.b0 = bfrag(wp, 0, (wc << 1), lane);
  pre.b.b1 = bfrag(wp, 0, (wc << 1) + 1, lane);

  // ---- prologue: pos-encode + gather z -> xyz tile (48 x 320 bf16) ----
  {
    const int g = tid >> 3, j = tid & 7;  // 8 threads per row; rows 0..47
    if (g < 48) {
      int grow = blockIdx.x * 48 + g;
      if (grow >= Btot) grow = Btot - 1;  // clamp tail (outputs guarded below)
      const float xv = xy[2 * grow], yv = xy[2 * grow + 1];
      const float rv = sqrtf(xv * xv + yv * yv);
      union { short s[8]; i32x4 v; } tmp;
#pragma unroll
      for (int i = 0; i < 8; ++i) {
        const int c = 8 * j + i;
        float fv;
        if (c < 2)       fv = c ? yv : xv;
        else if (c < 22) { int m = c - 2;  float f = 1.0f + (5.0f / 9.0f) * (m >> 1); fv = sinf(((m & 1) ? yv : xv) * f); }
        else if (c < 42) { int m = c - 22; float f = 1.0f + (5.0f / 9.0f) * (m >> 1); fv = cosf(((m & 1) ? yv : xv) * f); }
        else if (c < 44) fv = (c == 42) ? xv : yv;
        else if (c < 54) fv = sinf(rv * (1.0f + (5.0f / 9.0f) * (c - 44)));
        else             fv = cosf(rv * (1.0f + (5.0f / 9.0f) * (c - 54)));
        tmp.s[i] = f2bf(fv);
      }
      *(i32x4*)((char*)lds + swzaddr(0, 640, g, j << 4)) = tmp.v;
      const float* zr = emb + (size_t)(unsigned)idx[grow] * 256;
#pragma unroll
      for (int c4 = 0; c4 < 4; ++c4) {
        const int cel = j * 32 + c4 * 8;
        const float4 f0 = *(const float4*)(zr + cel);
        const float4 f1 = *(const float4*)(zr + cel + 4);
        union { short s[8]; i32x4 v; } t2;
        t2.s[0] = f2bf(f0.x); t2.s[1] = f2bf(f0.y); t2.s[2] = f2bf(f0.z); t2.s[3] = f2bf(f0.w);
        t2.s[4] = f2bf(f1.x); t2.s[5] = f2bf(f1.y); t2.s[6] = f2bf(f1.z); t2.s[7] = f2bf(f1.w);
        *(i32x4*)((char*)lds + swzaddr(0, 640, g, (64 + cel) << 1)) = t2.v;
      }
    }
  }
  ldsbar();

  // layer 1: a writes t; hard bar; b reads t, writes x (prefetches a(0)'s A)
  pre = do_gemm<10, 10, true,  false, false, false>(lds, 0, 640, 0, 640,
        wp, wp + 81920, b1a, TB, wc, lane, pre);
  ldsbar();
  pre = do_gemm<8, 8, false, false, false, true>(lds, TB, 512, TB, 512,
        wp + 81920, wp + 147456, b1b, XB, wc, lane, pre);
  // NO barrier here: mid-layer gemm-a carries it inside (MIDBAR)
  for (int l = 0; l < 8; ++l) {
    const short* wa = wp + 147456 + l * 147456;
    const short* wb = wp + 1327104 + l * 65536;
    const short* wan = (l < 7) ? (wa + 147456) : wp;  // dummy (valid mem) on last layer
    pre = do_gemm<18, 10, true, true, true, false>(lds, 0, 640, XB, 512,
          wa, wb, ba + l * 256, TB, wc, lane, pre);
    ldsbar();  // t ready (hard)
    pre = do_gemm<8, 8, false, false, false, true>(lds, TB, 512, TB, 512,
          wb, wan, bb + l * 256, XB, wc, lane, pre);
    // no trailing barrier: next a's MIDBAR (or the final ldsbar) covers it
  }
  ldsbar();  // x ready for the final reduce

  // final: out = x @ W2 + b2 ; 8 threads per row (32 cols each), width-8 reduce
  {
    const int r = tid >> 3, j = tid & 7;
    if (r < 48) {
      float sum = 0.f;
#pragma unroll
      for (int h = 0; h < 4; ++h) {
        const int cb = 64 * j + 16 * h;
        const s16x8 v = *(const s16x8*)((const char*)lds + swzaddr(XB, 512, r, cb));
        const int c0 = 32 * j + 8 * h;
        const float4 w0 = *(const float4*)(W2 + c0);
        const float4 w1 = *(const float4*)(W2 + c0 + 4);
        sum += bf2f(v[0]) * w0.x + bf2f(v[1]) * w0.y + bf2f(v[2]) * w0.z + bf2f(v[3]) * w0.w;
        sum += bf2f(v[4]) * w1.x + bf2f(v[5]) * w1.y + bf2f(v[6]) * w1.z + bf2f(v[7]) * w1.w;
      }
      sum += __shfl_xor(sum, 1); sum += __shfl_xor(sum, 2); sum += __shfl_xor(sum, 4);
      const int grow = blockIdx.x * 48 + r;
      if (j == 0 && grow < Btot) out[grow] = sum + b2[0];
    }
  }
}

extern "C" void kernel_launch(void* const* d_in, const int* in_sizes, int n_in,
                              void* d_out, int out_size, void* d_ws, size_t ws_size,
                              hipStream_t stream) {
  const float* xy  = (const float*)d_in[0];
  const int*   idx = (const int*)d_in[1];
  const float* emb = (const float*)d_in[2];
  const float* W1a = (const float*)d_in[3];
  const float* b1a = (const float*)d_in[4];
  const float* W1b = (const float*)d_in[5];
  const float* b1b = (const float*)d_in[6];
  const float* Wa  = (const float*)d_in[7];
  const float* ba  = (const float*)d_in[8];
  const float* Wb  = (const float*)d_in[9];
  const float* bb  = (const float*)d_in[10];
  const float* W2  = (const float*)d_in[11];
  const float* b2  = (const float*)d_in[12];
  short* ws = (short*)d_ws;
  const int B = in_sizes[1];

  hipLaunchKernelGGL(pack_weights_kernel, dim3(904), dim3(256), 0, stream,
                     W1a, W1b, Wa, Wb, ws);
  hipLaunchKernelGGL(geo2vec_kernel, dim3((B + 47) / 48), dim3(512), 0, stream,
                     xy, idx, emb, b1a, b1b, ba, bb, W2, b2, ws, (float*)d_out, B);
}